// Round 8
// baseline (216.261 us; speedup 1.0000x reference)
//
#include <hip/hip_runtime.h>
#include <cstdint>
#include <cstddef>

#define RADIX 258
#define EMPTY_ENTRY 0xFFFFFFFFFFFFFFFFULL
#define MAP_DIM 128                 // down coords are even, 0..254 -> /2 in 0..127
#define MAP_SLOTS (2 * MAP_DIM * MAP_DIM * MAP_DIM)   // 4.19M slots = 16 MiB
#define NB_WORDS 8                  // 32-B row: idx0..idx7 inline
#define EXT_WORDS 19                // spill for indices 8..26 (rare)

typedef float f32x4 __attribute__((ext_vector_type(4)));

// ---------------------------------------------------------------------------
// FAST PATH: dense parent map + compact cnt + 32-B nbmap rows +
//            branchless 2-iter-cover pipelined gather, residency-sized grid
// ---------------------------------------------------------------------------

__global__ __launch_bounds__(256) void build_map_kernel(
    const int* __restrict__ down, int M, unsigned* __restrict__ map)
{
    int j = blockIdx.x * blockDim.x + threadIdx.x;
    if (j >= M) return;
    const int4 c = ((const int4*)down)[j];
    unsigned idx = (((unsigned)(c.w * MAP_DIM + (c.x >> 1)) * MAP_DIM)
                    + (unsigned)(c.y >> 1)) * MAP_DIM + (unsigned)(c.z >> 1);
    map[idx] = (unsigned)j;
}

// Append input row i to each existing candidate parent's list.
// cnt: compact L2-resident atomic array. First 8 indices inline (32-B row),
// overflow (pos>=8, rare) to ext.
__global__ __launch_bounds__(256) void scatter_kernel(
    const int* __restrict__ coords, int N,
    const unsigned* __restrict__ map,
    unsigned* __restrict__ cnt, unsigned* __restrict__ nbmap,
    unsigned* __restrict__ ext)
{
    int i = blockIdx.x * blockDim.x + threadIdx.x;
    if (i >= N) return;
    const int4 c = ((const int4*)coords)[i];
    int qx[2], qy[2], qz[2];
    int nx = 1, ny = 1, nz = 1;
    if (c.x & 1) { qx[0] = (c.x - 1) >> 1; if (c.x + 1 <= 254) qx[nx++] = (c.x + 1) >> 1; }
    else         { qx[0] = c.x >> 1; }
    if (c.y & 1) { qy[0] = (c.y - 1) >> 1; if (c.y + 1 <= 254) qy[ny++] = (c.y + 1) >> 1; }
    else         { qy[0] = c.y >> 1; }
    if (c.z & 1) { qz[0] = (c.z - 1) >> 1; if (c.z + 1 <= 254) qz[nz++] = (c.z + 1) >> 1; }
    else         { qz[0] = c.z >> 1; }
    unsigned bbase = (unsigned)(c.w * MAP_DIM);
    for (int ix = 0; ix < nx; ++ix) {
        unsigned xb = (bbase + (unsigned)qx[ix]) * MAP_DIM;
        for (int iy = 0; iy < ny; ++iy) {
            unsigned yb = (xb + (unsigned)qy[iy]) * MAP_DIM;
            for (int iz = 0; iz < nz; ++iz) {
                unsigned qi = map[yb + (unsigned)qz[iz]];
                if (qi != 0xFFFFFFFFu) {
                    unsigned pos = atomicAdd(&cnt[qi], 1u);
                    if (pos < NB_WORDS)
                        nbmap[(size_t)qi * NB_WORDS + pos] = (unsigned)i;
                    else
                        ext[(size_t)qi * EXT_WORDS + (pos - NB_WORDS)] = (unsigned)i;
                }
            }
        }
    }
}

// Persistent grid-stride gather; 4 rows per wave-iteration (16-lane groups;
// lane j = channel quad j). Meta group-uniform (HW broadcast, no shuffles);
// feats loads unconditional (clamped indices; dup loads idempotent under max).
// Covers: meta 4 iters ahead, feats issued 2 iters before consume.
// __launch_bounds__(256,4): cap VGPR at 128 so 4 blocks/CU are resident; the
// host sizes the grid to EXACTLY the resident capacity (no serialized sets).
__global__ __launch_bounds__(256, 4) void gather_kernel(
    const float* __restrict__ feats,
    const unsigned* __restrict__ cnt,
    const unsigned* __restrict__ nbmap,
    const unsigned* __restrict__ ext,
    float* __restrict__ out, int M, int nblk)
{
    // bijective XCD-chunked block swizzle (8 XCDs)
    int bid = blockIdx.x;
    int q8 = nblk >> 3, r8 = nblk & 7;
    int xcd = bid & 7, orig = bid >> 3;
    int swz = (xcd < r8 ? xcd * (q8 + 1) : r8 * (q8 + 1) + (xcd - r8) * q8) + orig;

    int lane = threadIdx.x & 63;
    int g  = lane >> 4;            // row within the quad
    int j  = lane & 15;            // channel quad
    int wv = swz * 4 + (int)(threadIdx.x >> 6);
    int T  = nblk * 4;             // quad stride
    int nq = (M + 3) >> 2;

    const f32x4* f4  = (const f32x4*)feats;
    const int4*  nb4 = (const int4*)nbmap;     // 2 int4 per row

    auto rowof = [&](int qq) -> int {
        int qc = qq < nq ? qq : nq - 1;        // clamp: tail work duplicates
        int r = qc * 4 + g;                    //   real rows (identical data,
        return r < M ? r : M - 1;              //   benign duplicate stores)
    };
    auto load_meta = [&](int qq, int& c, int4& idx) {
        int r = rowof(qq);
        c   = (int)cnt[r];                     // group-uniform -> broadcast
        idx = nb4[(size_t)r * 2];              // group-uniform -> broadcast
    };
    auto issue_feats = [&](int c, int4 idx,
                           f32x4& w0, f32x4& w1, f32x4& w2, f32x4& w3) {
        int s0 = c > 0 ? idx.x : 0;            // branchless clamp; always load
        int s1 = c > 1 ? idx.y : s0;
        int s2 = c > 2 ? idx.z : s0;
        int s3 = c > 3 ? idx.w : s0;
        w0 = f4[(size_t)s0 * 16 + j];
        w1 = f4[(size_t)s1 * 16 + j];
        w2 = f4[(size_t)s2 * 16 + j];
        w3 = f4[(size_t)s3 * 16 + j];
    };

    // ---- prologue ----
    int q = wv;
    int cA; int4 iA; load_meta(q,         cA, iA);
    int cB; int4 iB; load_meta(q + T,     cB, iB);
    int c2; int4 i2; load_meta(q + 2 * T, c2, i2);
    int c3; int4 i3; load_meta(q + 3 * T, c3, i3);

    f32x4 v0, v1, v2, v3, p0, p1, p2, p3, w0, w1, w2, w3;
    issue_feats(cA, iA, v0, v1, v2, v3);       // feats for quad q
    issue_feats(cB, iB, p0, p1, p2, p3);       // feats for quad q+T
    int c0 = cA, c1 = cB;

    // ---- main loop ----
    for (; q < nq; q += T) {
        int cN; int4 iN; load_meta(q + 4 * T, cN, iN);   // meta 4 ahead
        issue_feats(c2, i2, w0, w1, w2, w3);             // feats for q+2T
        int cPush = c2;

        // consume quad q (feats issued 2 iterations ago)
        {
            int row = rowof(q);
            f32x4 acc;
            acc.x = fmaxf(fmaxf(v0.x, v1.x), fmaxf(v2.x, v3.x));
            acc.y = fmaxf(fmaxf(v0.y, v1.y), fmaxf(v2.y, v3.y));
            acc.z = fmaxf(fmaxf(v0.z, v1.z), fmaxf(v2.z, v3.z));
            acc.w = fmaxf(fmaxf(v0.w, v1.w), fmaxf(v2.w, v3.w));
            int c = c0;
            if (c > 4) {                       // rare overflow path
                int4 e = nb4[(size_t)row * 2 + 1];
                int cc = c < 8 ? c : 8;
                f32x4 t;
                if (cc > 4) { t = f4[(size_t)e.x * 16 + j];
                    acc.x = fmaxf(acc.x, t.x); acc.y = fmaxf(acc.y, t.y);
                    acc.z = fmaxf(acc.z, t.z); acc.w = fmaxf(acc.w, t.w); }
                if (cc > 5) { t = f4[(size_t)e.y * 16 + j];
                    acc.x = fmaxf(acc.x, t.x); acc.y = fmaxf(acc.y, t.y);
                    acc.z = fmaxf(acc.z, t.z); acc.w = fmaxf(acc.w, t.w); }
                if (cc > 6) { t = f4[(size_t)e.z * 16 + j];
                    acc.x = fmaxf(acc.x, t.x); acc.y = fmaxf(acc.y, t.y);
                    acc.z = fmaxf(acc.z, t.z); acc.w = fmaxf(acc.w, t.w); }
                if (cc > 7) { t = f4[(size_t)e.w * 16 + j];
                    acc.x = fmaxf(acc.x, t.x); acc.y = fmaxf(acc.y, t.y);
                    acc.z = fmaxf(acc.z, t.z); acc.w = fmaxf(acc.w, t.w); }
                for (int h = 8; h < c; ++h) {
                    int s = (int)ext[(size_t)row * EXT_WORDS + (h - 8)];
                    t = f4[(size_t)s * 16 + j];
                    acc.x = fmaxf(acc.x, t.x); acc.y = fmaxf(acc.y, t.y);
                    acc.z = fmaxf(acc.z, t.z); acc.w = fmaxf(acc.w, t.w);
                }
            }
            if (c == 0) acc = (f32x4){0.f, 0.f, 0.f, 0.f};   // defensive
            __builtin_nontemporal_store(acc, (f32x4*)out + (size_t)row * 16 + j);
        }

        // rotate pipeline (all static, named registers)
        v0 = p0; v1 = p1; v2 = p2; v3 = p3;
        p0 = w0; p1 = w1; p2 = w2; p3 = w3;
        c0 = c1; c1 = cPush;
        c2 = c3; i2 = i3;
        c3 = cN; i3 = iN;
    }
}

// ---------------------------------------------------------------------------
// FALLBACK PATH (round-1 proven kernels) if ws is too small
// ---------------------------------------------------------------------------

__global__ __launch_bounds__(256) void build_hash_kernel(
    const int* __restrict__ coords, int N,
    unsigned long long* __restrict__ tab, unsigned tmask, int tshift)
{
    int i = blockIdx.x * blockDim.x + threadIdx.x;
    if (i >= N) return;
    int x = coords[i * 4 + 0];
    int y = coords[i * 4 + 1];
    int z = coords[i * 4 + 2];
    int b = coords[i * 4 + 3];
    unsigned key = ((unsigned)(b * RADIX + x + 1) * RADIX + (unsigned)(y + 1)) * RADIX
                   + (unsigned)(z + 1);
    unsigned long long entry = ((unsigned long long)key << 32) | (unsigned)i;
    unsigned slot = (key * 2654435761u) >> tshift;
    while (true) {
        unsigned long long prev = atomicCAS(&tab[slot], EMPTY_ENTRY, entry);
        if (prev == EMPTY_ENTRY) break;
        slot = (slot + 1) & tmask;
    }
}

__global__ __launch_bounds__(256) void pool_kernel(
    const float* __restrict__ feats,
    const int* __restrict__ down, int M,
    const unsigned long long* __restrict__ tab, unsigned tmask, int tshift,
    float* __restrict__ out)
{
    int wave = (int)((blockIdx.x * blockDim.x + threadIdx.x) >> 6);
    int lane = threadIdx.x & 63;
    if (wave >= M) return;

    const int* dc = down + (size_t)wave * 4;
    int dx = dc[0], dy = dc[1], dz = dc[2], db = dc[3];
    unsigned base = ((unsigned)(db * RADIX + dx + 1) * RADIX + (unsigned)(dy + 1)) * RADIX
                    + (unsigned)(dz + 1);

    int src = -1;
    if (lane < 27) {
        int ox = lane % 3 - 1;
        int oy = (lane / 3) % 3 - 1;
        int oz = lane / 9 - 1;
        int delta = ox * (RADIX * RADIX) + oy * RADIX + oz;
        unsigned key = (unsigned)((int)base + delta);
        unsigned slot = (key * 2654435761u) >> tshift;
        while (true) {
            unsigned long long e = tab[slot];
            if (e == EMPTY_ENTRY) break;
            if ((unsigned)(e >> 32) == key) { src = (int)(unsigned)e; break; }
            slot = (slot + 1) & tmask;
        }
    }
    unsigned long long mask = __ballot(src >= 0);
    float acc = -INFINITY;
    while (mask) {
        int bit = __ffsll(mask) - 1;
        int s = __shfl(src, bit);
        acc = fmaxf(acc, feats[(size_t)s * 64 + lane]);
        mask &= mask - 1;
    }
    out[(size_t)wave * 64 + lane] = isinf(acc) ? 0.0f : acc;
}

// ---------------------------------------------------------------------------

extern "C" void kernel_launch(void* const* d_in, const int* in_sizes, int n_in,
                              void* d_out, int out_size, void* d_ws, size_t ws_size,
                              hipStream_t stream)
{
    const float* feats  = (const float*)d_in[0];
    const int*   coords = (const int*)d_in[1];
    const int*   down   = (const int*)d_in[2];
    float*       out    = (float*)d_out;

    int N = in_sizes[1] / 4;
    int M = in_sizes[2] / 4;

    size_t map_bytes = (size_t)MAP_SLOTS * 4;                    // 16 MiB
    size_t cnt_bytes = ((size_t)M * 4 + 127) & ~(size_t)127;
    size_t nb_bytes  = (size_t)(M + 4) * NB_WORDS * 4;           // 32 B per row
    size_t ext_bytes = (size_t)M * EXT_WORDS * 4;
    size_t need = map_bytes + cnt_bytes + nb_bytes + ext_bytes;  // ~135 MB

    if (ws_size >= need) {
        char* p = (char*)d_ws;
        unsigned* map   = (unsigned*)p;                 p += map_bytes;
        unsigned* cnt   = (unsigned*)p;                 p += cnt_bytes;
        unsigned* nbmap = (unsigned*)p;                 p += nb_bytes;
        unsigned* ext   = (unsigned*)p;

        hipMemsetAsync(map, 0xFF, map_bytes, stream);            // HW fill
        hipMemsetAsync(cnt, 0x00, (size_t)M * 4, stream);

        build_map_kernel<<<(M + 255) / 256, 256, 0, stream>>>(down, M, map);
        scatter_kernel<<<(N + 255) / 256, 256, 0, stream>>>(coords, N, map, cnt, nbmap, ext);

        // Size the persistent grid to EXACT residency: launched == resident.
        int blocksPerCU = 0;
        (void)hipOccupancyMaxActiveBlocksPerMultiprocessor(
            &blocksPerCU, (const void*)gather_kernel, 256, 0);
        if (blocksPerCU < 1) blocksPerCU = 1;
        int nblk = blocksPerCU * 256;                  // 256 CUs on MI355X
        int nq = (M + 3) / 4;
        int maxBlk = (nq + 3) / 4;
        if (nblk > maxBlk) nblk = maxBlk;
        if (nblk > 2048) nblk = 2048;
        gather_kernel<<<nblk, 256, 0, stream>>>(feats, cnt, nbmap, ext, out, M, nblk);
    } else {
        int logT = 22;
        while (logT > 19 && ((size_t)8u << logT) > ws_size) logT--;
        unsigned T = 1u << logT;
        unsigned tmask = T - 1u;
        int tshift = 32 - logT;
        unsigned long long* tab = (unsigned long long*)d_ws;
        hipMemsetAsync(tab, 0xFF, (size_t)T * 8, stream);
        build_hash_kernel<<<(N + 255) / 256, 256, 0, stream>>>(coords, N, tab, tmask, tshift);
        pool_kernel<<<(M * 64 + 255) / 256, 256, 0, stream>>>(
            feats, down, M, tab, tmask, tshift, out);
    }
}

// Round 9
// 194.038 us; speedup vs baseline: 1.1145x; 1.1145x over previous
//
#include <hip/hip_runtime.h>
#include <cstdint>
#include <cstddef>

#define RADIX 258
#define EMPTY_ENTRY 0xFFFFFFFFFFFFFFFFULL
#define MAP_DIM 128                 // down coords are even, 0..254 -> /2 in 0..127
#define MAP_SLOTS (2 * MAP_DIM * MAP_DIM * MAP_DIM)   // 4.19M slots = 16 MiB
#define NB_WORDS 8                  // 32-B row: idx0..idx7 inline
#define EXT_WORDS 19                // spill for indices 8..26 (rare)

typedef float f32x4 __attribute__((ext_vector_type(4)));

// ---------------------------------------------------------------------------
// FAST PATH: dense parent map + compact cnt + 32-B nbmap rows +
//            modulo-3 unrolled pipelined gather (no pending-reg copies)
// ---------------------------------------------------------------------------

__global__ __launch_bounds__(256) void build_map_kernel(
    const int* __restrict__ down, int M, unsigned* __restrict__ map)
{
    int j = blockIdx.x * blockDim.x + threadIdx.x;
    if (j >= M) return;
    const int4 c = ((const int4*)down)[j];
    unsigned idx = (((unsigned)(c.w * MAP_DIM + (c.x >> 1)) * MAP_DIM)
                    + (unsigned)(c.y >> 1)) * MAP_DIM + (unsigned)(c.z >> 1);
    map[idx] = (unsigned)j;
}

__global__ __launch_bounds__(256) void scatter_kernel(
    const int* __restrict__ coords, int N,
    const unsigned* __restrict__ map,
    unsigned* __restrict__ cnt, unsigned* __restrict__ nbmap,
    unsigned* __restrict__ ext)
{
    int i = blockIdx.x * blockDim.x + threadIdx.x;
    if (i >= N) return;
    const int4 c = ((const int4*)coords)[i];
    int qx[2], qy[2], qz[2];
    int nx = 1, ny = 1, nz = 1;
    if (c.x & 1) { qx[0] = (c.x - 1) >> 1; if (c.x + 1 <= 254) qx[nx++] = (c.x + 1) >> 1; }
    else         { qx[0] = c.x >> 1; }
    if (c.y & 1) { qy[0] = (c.y - 1) >> 1; if (c.y + 1 <= 254) qy[ny++] = (c.y + 1) >> 1; }
    else         { qy[0] = c.y >> 1; }
    if (c.z & 1) { qz[0] = (c.z - 1) >> 1; if (c.z + 1 <= 254) qz[nz++] = (c.z + 1) >> 1; }
    else         { qz[0] = c.z >> 1; }
    unsigned bbase = (unsigned)(c.w * MAP_DIM);
    for (int ix = 0; ix < nx; ++ix) {
        unsigned xb = (bbase + (unsigned)qx[ix]) * MAP_DIM;
        for (int iy = 0; iy < ny; ++iy) {
            unsigned yb = (xb + (unsigned)qy[iy]) * MAP_DIM;
            for (int iz = 0; iz < nz; ++iz) {
                unsigned qi = map[yb + (unsigned)qz[iz]];
                if (qi != 0xFFFFFFFFu) {
                    unsigned pos = atomicAdd(&cnt[qi], 1u);
                    if (pos < NB_WORDS)
                        nbmap[(size_t)qi * NB_WORDS + pos] = (unsigned)i;
                    else
                        ext[(size_t)qi * EXT_WORDS + (pos - NB_WORDS)] = (unsigned)i;
                }
            }
        }
    }
}

// Persistent grid-stride gather; 4 rows per wave-stage (16-lane groups; lane
// j = channel quad j). Steady-state loop is unrolled 3x with three NAMED
// feats/meta register sets so no register copy ever targets a pending load:
//   stage processing quad P: issue feats(P+2T) from meta loaded 2 stages ago,
//   reload that meta set with meta(P+4T), consume feats(P) (issued 2 stages
//   ago), store. The only per-stage wait is for the 2-stage-old set; 2 full
//   stages of loads remain in flight across it.
__global__ __launch_bounds__(256, 4) void gather_kernel(
    const float* __restrict__ feats,
    const unsigned* __restrict__ cnt,
    const unsigned* __restrict__ nbmap,
    const unsigned* __restrict__ ext,
    float* __restrict__ out, int M, int nblk)
{
    // bijective XCD-chunked block swizzle (8 XCDs)
    int bid = blockIdx.x;
    int q8 = nblk >> 3, r8 = nblk & 7;
    int xcd = bid & 7, orig = bid >> 3;
    int swz = (xcd < r8 ? xcd * (q8 + 1) : r8 * (q8 + 1) + (xcd - r8) * q8) + orig;

    int lane = threadIdx.x & 63;
    int g  = lane >> 4;            // row within the quad
    int j  = lane & 15;            // channel quad
    int wv = swz * 4 + (int)(threadIdx.x >> 6);
    int T  = nblk * 4;             // quad stride
    int nq = (M + 3) >> 2;

    const f32x4* f4  = (const f32x4*)feats;
    const int4*  nb4 = (const int4*)nbmap;     // 2 int4 per row

    auto rowof = [&](int qq) -> int {
        int qc = qq < nq ? qq : nq - 1;        // clamp: tail duplicates real
        int r = qc * 4 + g;                    //   rows (identical data =>
        return r < M ? r : M - 1;              //   benign duplicate stores)
    };
    auto load_meta = [&](int qq, int& c, int4& idx) {
        int r = rowof(qq);
        c   = (int)cnt[r];                     // group-uniform -> broadcast
        idx = nb4[(size_t)r * 2];              // group-uniform -> broadcast
    };
    auto issue4 = [&](int c, int4 idx,
                      f32x4& w0, f32x4& w1, f32x4& w2, f32x4& w3) {
        int s0 = c > 0 ? idx.x : 0;            // branchless clamp; always load
        int s1 = c > 1 ? idx.y : s0;
        int s2 = c > 2 ? idx.z : s0;
        int s3 = c > 3 ? idx.w : s0;
        w0 = f4[(size_t)s0 * 16 + j];
        w1 = f4[(size_t)s1 * 16 + j];
        w2 = f4[(size_t)s2 * 16 + j];
        w3 = f4[(size_t)s3 * 16 + j];
    };
    auto consume = [&](f32x4 v0, f32x4 v1, f32x4 v2, f32x4 v3, int c, int qq) {
        int row = rowof(qq);
        f32x4 acc;
        acc.x = fmaxf(fmaxf(v0.x, v1.x), fmaxf(v2.x, v3.x));
        acc.y = fmaxf(fmaxf(v0.y, v1.y), fmaxf(v2.y, v3.y));
        acc.z = fmaxf(fmaxf(v0.z, v1.z), fmaxf(v2.z, v3.z));
        acc.w = fmaxf(fmaxf(v0.w, v1.w), fmaxf(v2.w, v3.w));
        if (c > 4) {                            // rare overflow path
            int4 e = nb4[(size_t)row * 2 + 1];
            int cc = c < 8 ? c : 8;
            f32x4 t;
            if (cc > 4) { t = f4[(size_t)e.x * 16 + j];
                acc.x = fmaxf(acc.x, t.x); acc.y = fmaxf(acc.y, t.y);
                acc.z = fmaxf(acc.z, t.z); acc.w = fmaxf(acc.w, t.w); }
            if (cc > 5) { t = f4[(size_t)e.y * 16 + j];
                acc.x = fmaxf(acc.x, t.x); acc.y = fmaxf(acc.y, t.y);
                acc.z = fmaxf(acc.z, t.z); acc.w = fmaxf(acc.w, t.w); }
            if (cc > 6) { t = f4[(size_t)e.z * 16 + j];
                acc.x = fmaxf(acc.x, t.x); acc.y = fmaxf(acc.y, t.y);
                acc.z = fmaxf(acc.z, t.z); acc.w = fmaxf(acc.w, t.w); }
            if (cc > 7) { t = f4[(size_t)e.w * 16 + j];
                acc.x = fmaxf(acc.x, t.x); acc.y = fmaxf(acc.y, t.y);
                acc.z = fmaxf(acc.z, t.z); acc.w = fmaxf(acc.w, t.w); }
            for (int h = 8; h < c; ++h) {
                int s = (int)ext[(size_t)row * EXT_WORDS + (h - 8)];
                t = f4[(size_t)s * 16 + j];
                acc.x = fmaxf(acc.x, t.x); acc.y = fmaxf(acc.y, t.y);
                acc.z = fmaxf(acc.z, t.z); acc.w = fmaxf(acc.w, t.w);
            }
        }
        if (c == 0) acc = (f32x4){0.f, 0.f, 0.f, 0.f};   // defensive
        __builtin_nontemporal_store(acc, (f32x4*)out + (size_t)row * 16 + j);
    };

    // ---- prologue ----
    int q = wv;
    int m0c; int4 m0i; load_meta(q,         m0c, m0i);
    int m1c; int4 m1i; load_meta(q + T,     m1c, m1i);
    f32x4 f00, f01, f02, f03, f10, f11, f12, f13, f20, f21, f22, f23;
    issue4(m0c, m0i, f00, f01, f02, f03);  int cs0 = m0c;   // feats(q)
    issue4(m1c, m1i, f10, f11, f12, f13);  int cs1 = m1c;   // feats(q+T)
    int m2c; int4 m2i; load_meta(q + 2 * T, m2c, m2i);
    load_meta(q + 3 * T, m0c, m0i);                          // set0 := meta(q+3T)
    int cs2;

    // ---- steady loop: 3 stages per trip, no pending-reg copies ----
    for (; q < nq; q += 3 * T) {
        // stage A: quad q
        issue4(m2c, m2i, f20, f21, f22, f23);  cs2 = m2c;    // feats(q+2T)
        load_meta(q + 4 * T, m1c, m1i);
        consume(f00, f01, f02, f03, cs0, q);
        // stage B: quad q+T
        issue4(m0c, m0i, f00, f01, f02, f03);  cs0 = m0c;    // feats(q+3T)
        load_meta(q + 5 * T, m2c, m2i);
        consume(f10, f11, f12, f13, cs1, q + T);
        // stage C: quad q+2T
        issue4(m1c, m1i, f10, f11, f12, f13);  cs1 = m1c;    // feats(q+4T)
        load_meta(q + 6 * T, m0c, m0i);
        consume(f20, f21, f22, f23, cs2, q + 2 * T);
    }
}

// ---------------------------------------------------------------------------
// FALLBACK PATH (round-1 proven kernels) if ws is too small
// ---------------------------------------------------------------------------

__global__ __launch_bounds__(256) void build_hash_kernel(
    const int* __restrict__ coords, int N,
    unsigned long long* __restrict__ tab, unsigned tmask, int tshift)
{
    int i = blockIdx.x * blockDim.x + threadIdx.x;
    if (i >= N) return;
    int x = coords[i * 4 + 0];
    int y = coords[i * 4 + 1];
    int z = coords[i * 4 + 2];
    int b = coords[i * 4 + 3];
    unsigned key = ((unsigned)(b * RADIX + x + 1) * RADIX + (unsigned)(y + 1)) * RADIX
                   + (unsigned)(z + 1);
    unsigned long long entry = ((unsigned long long)key << 32) | (unsigned)i;
    unsigned slot = (key * 2654435761u) >> tshift;
    while (true) {
        unsigned long long prev = atomicCAS(&tab[slot], EMPTY_ENTRY, entry);
        if (prev == EMPTY_ENTRY) break;
        slot = (slot + 1) & tmask;
    }
}

__global__ __launch_bounds__(256) void pool_kernel(
    const float* __restrict__ feats,
    const int* __restrict__ down, int M,
    const unsigned long long* __restrict__ tab, unsigned tmask, int tshift,
    float* __restrict__ out)
{
    int wave = (int)((blockIdx.x * blockDim.x + threadIdx.x) >> 6);
    int lane = threadIdx.x & 63;
    if (wave >= M) return;

    const int* dc = down + (size_t)wave * 4;
    int dx = dc[0], dy = dc[1], dz = dc[2], db = dc[3];
    unsigned base = ((unsigned)(db * RADIX + dx + 1) * RADIX + (unsigned)(dy + 1)) * RADIX
                    + (unsigned)(dz + 1);

    int src = -1;
    if (lane < 27) {
        int ox = lane % 3 - 1;
        int oy = (lane / 3) % 3 - 1;
        int oz = lane / 9 - 1;
        int delta = ox * (RADIX * RADIX) + oy * RADIX + oz;
        unsigned key = (unsigned)((int)base + delta);
        unsigned slot = (key * 2654435761u) >> tshift;
        while (true) {
            unsigned long long e = tab[slot];
            if (e == EMPTY_ENTRY) break;
            if ((unsigned)(e >> 32) == key) { src = (int)(unsigned)e; break; }
            slot = (slot + 1) & tmask;
        }
    }
    unsigned long long mask = __ballot(src >= 0);
    float acc = -INFINITY;
    while (mask) {
        int bit = __ffsll(mask) - 1;
        int s = __shfl(src, bit);
        acc = fmaxf(acc, feats[(size_t)s * 64 + lane]);
        mask &= mask - 1;
    }
    out[(size_t)wave * 64 + lane] = isinf(acc) ? 0.0f : acc;
}

// ---------------------------------------------------------------------------

extern "C" void kernel_launch(void* const* d_in, const int* in_sizes, int n_in,
                              void* d_out, int out_size, void* d_ws, size_t ws_size,
                              hipStream_t stream)
{
    const float* feats  = (const float*)d_in[0];
    const int*   coords = (const int*)d_in[1];
    const int*   down   = (const int*)d_in[2];
    float*       out    = (float*)d_out;

    int N = in_sizes[1] / 4;
    int M = in_sizes[2] / 4;

    size_t map_bytes = (size_t)MAP_SLOTS * 4;                    // 16 MiB
    size_t cnt_bytes = ((size_t)M * 4 + 127) & ~(size_t)127;
    size_t nb_bytes  = (size_t)(M + 4) * NB_WORDS * 4;           // 32 B per row
    size_t ext_bytes = (size_t)M * EXT_WORDS * 4;
    size_t need = map_bytes + cnt_bytes + nb_bytes + ext_bytes;  // ~135 MB

    if (ws_size >= need) {
        char* p = (char*)d_ws;
        unsigned* map   = (unsigned*)p;                 p += map_bytes;
        unsigned* cnt   = (unsigned*)p;                 p += cnt_bytes;
        unsigned* nbmap = (unsigned*)p;                 p += nb_bytes;
        unsigned* ext   = (unsigned*)p;

        hipMemsetAsync(map, 0xFF, map_bytes, stream);            // HW fill
        hipMemsetAsync(cnt, 0x00, (size_t)M * 4, stream);

        build_map_kernel<<<(M + 255) / 256, 256, 0, stream>>>(down, M, map);
        scatter_kernel<<<(N + 255) / 256, 256, 0, stream>>>(coords, N, map, cnt, nbmap, ext);

        // Size the persistent grid to residency: launched == resident.
        int blocksPerCU = 0;
        (void)hipOccupancyMaxActiveBlocksPerMultiprocessor(
            &blocksPerCU, (const void*)gather_kernel, 256, 0);
        if (blocksPerCU < 1) blocksPerCU = 1;
        int nblk = blocksPerCU * 256;                  // 256 CUs on MI355X
        int nq = (M + 3) / 4;
        int maxBlk = (nq + 3) / 4;
        if (nblk > maxBlk) nblk = maxBlk;
        if (nblk > 2048) nblk = 2048;
        gather_kernel<<<nblk, 256, 0, stream>>>(feats, cnt, nbmap, ext, out, M, nblk);
    } else {
        int logT = 22;
        while (logT > 19 && ((size_t)8u << logT) > ws_size) logT--;
        unsigned T = 1u << logT;
        unsigned tmask = T - 1u;
        int tshift = 32 - logT;
        unsigned long long* tab = (unsigned long long*)d_ws;
        hipMemsetAsync(tab, 0xFF, (size_t)T * 8, stream);
        build_hash_kernel<<<(N + 255) / 256, 256, 0, stream>>>(coords, N, tab, tmask, tshift);
        pool_kernel<<<(M * 64 + 255) / 256, 256, 0, stream>>>(
            feats, down, M, tab, tmask, tshift, out);
    }
}